// Round 1
// baseline (691.146 us; speedup 1.0000x reference)
//
#include <hip/hip_runtime.h>

// ---------------------------------------------------------------------------
// UltimateV6: dynamic-routing MoE-style net. Key insight: top-k depends only
// on batch row 0 -> precompute the 8 (layer,block) selections in a tiny
// kernel, then the 131072-row batch is a static chain of 8 FFN blocks.
// Main kernel: bf16 MFMA 16x16x32, h fp32-resident in LDS, waves split N so
// weights are fragment-packed and read coalesced from L2 once per block-stage.
// ---------------------------------------------------------------------------

typedef __attribute__((ext_vector_type(8))) short s16x8;
typedef __attribute__((ext_vector_type(4))) float f32x4;
typedef unsigned short ushort_t;

#define BATCH 131072
#define TBROWS 128
#define LDS_HSTR 130   // h row stride in floats: 130 -> 2-way (free) LDS conflicts on scatter

// ws layout (bytes)
#define WS_IDX 0        // int[8]
#define WS_PRM 64       // float[8][768]: ln_s128 ln_b128 b1x256 b2x128 te128
#define WS_PB  24640    // float[128]: proj_b + pos
#define WS_PW  25152    // ushort[4096]: proj_w frag-packed bf16
#define WS_W1  33344    // ushort[8][32768]
#define WS_W2  557632   // ushort[8][32768]

__device__ inline ushort_t f2bf(float f) {
  unsigned u = __float_as_uint(f);
  u += 0x7fffu + ((u >> 16) & 1u);
  return (ushort_t)(u >> 16);
}

// gelu ~= x * sigmoid(1.702 x); |err| vs exact erf-gelu ~<5e-3 on |x|<1.5,
// decorrelated through random w2 (gain 0.32) and 0.5 residual scale.
__device__ inline float geluf(float v) {
  float e = __builtin_amdgcn_exp2f(-2.4554670f * v);
  return v * __builtin_amdgcn_rcpf(1.0f + e);
}

// ---------------------------------------------------------------------------
// Kernel A: row-0 trajectory in exact fp32 (erff), emit 8 selected indices.
// ---------------------------------------------------------------------------
__global__ __launch_bounds__(256) void uv6_select(
    const float* __restrict__ x, const float* __restrict__ proj_w,
    const float* __restrict__ proj_b, const float* __restrict__ pos,
    const float* __restrict__ sel_w, const float* __restrict__ sel_b,
    const float* __restrict__ ln_s, const float* __restrict__ ln_b,
    const float* __restrict__ w1, const float* __restrict__ b1,
    const float* __restrict__ w2, const float* __restrict__ b2,
    const float* __restrict__ gate, const float* __restrict__ tf,
    int* __restrict__ wsI) {
  __shared__ float h0[128], hn[128], z1[256], red[256], adjs[8];
  __shared__ int top[2];
  __shared__ float muS, rstdS;
  int t = threadIdx.x;
  if (t < 128) {
    float a = proj_b[t] + pos[t];
#pragma unroll 4
    for (int f = 0; f < 32; ++f) a += x[f] * proj_w[f * 128 + t];
    h0[t] = a;
  }
  __syncthreads();
  for (int l = 0; l < 4; ++l) {
    if (t < 8) {
      float sc = sel_b[l * 8 + t];
#pragma unroll 8
      for (int d = 0; d < 128; ++d) sc += h0[d] * sel_w[(l * 128 + d) * 8 + t];
      sc = 1.0f / (1.0f + __expf(-sc));
      adjs[t] = sc * 0.6f + 0.2f;  // priority 0.5 * 0.4
    }
    __syncthreads();
    if (t == 0) {
      int i0 = 0; float v0 = adjs[0];
      for (int j = 1; j < 8; ++j) if (adjs[j] > v0) { v0 = adjs[j]; i0 = j; }
      int i1 = -1; float v1 = -1e30f;
      for (int j = 0; j < 8; ++j) if (j != i0 && adjs[j] > v1) { v1 = adjs[j]; i1 = j; }
      top[0] = i0; top[1] = i1;
      wsI[2 * l] = i0; wsI[2 * l + 1] = i1;
    }
    __syncthreads();
    for (int kk = 0; kk < 2; ++kk) {
      int base = l * 8 + top[kk];
      red[t] = (t < 128) ? h0[t] : 0.0f;
      __syncthreads();
      for (int off = 128; off > 0; off >>= 1) {
        if (t < off) red[t] += red[t + off];
        __syncthreads();
      }
      if (t == 0) muS = red[0] * (1.0f / 128.0f);
      __syncthreads();
      float mu = muS;
      red[t] = 0.0f;
      if (t < 128) { float d = h0[t] - mu; red[t] = d * d; }
      __syncthreads();
      for (int off = 128; off > 0; off >>= 1) {
        if (t < off) red[t] += red[t + off];
        __syncthreads();
      }
      if (t == 0) rstdS = rsqrtf(red[0] * (1.0f / 128.0f) + 1e-5f);
      __syncthreads();
      if (t < 128)
        hn[t] = (h0[t] - mu) * rstdS * ln_s[base * 128 + t] + ln_b[base * 128 + t];
      __syncthreads();
      {
        float a = b1[base * 256 + t];
#pragma unroll 8
        for (int d = 0; d < 128; ++d) a += hn[d] * w1[(base * 128 + d) * 256 + t];
        a = 0.5f * a * (1.0f + erff(a * 0.70710678118f));  // exact gelu
        z1[t] = a;
      }
      __syncthreads();
      {
        int d = t & 127, part = t >> 7;
        float a = 0.0f;
#pragma unroll 8
        for (int n = part * 128; n < part * 128 + 128; ++n)
          a += z1[n] * w2[(base * 256 + n) * 128 + d];
        red[t] = a;
      }
      __syncthreads();
      if (t < 128) {
        float z2 = red[t] + red[t + 128] + b2[base * 128 + t];
        float te = tf[t] * (1.0f / (1.0f + __expf(-gate[base * 128 + t])));
        h0[t] += 0.5f * z2 * (1.0f + te);
      }
      __syncthreads();
    }
  }
}

// ---------------------------------------------------------------------------
// Kernel P: pack per-stage params + proj_w fragments + proj_b+pos.
// ---------------------------------------------------------------------------
__global__ __launch_bounds__(256) void uv6_params(
    const float* __restrict__ ln_s, const float* __restrict__ ln_b,
    const float* __restrict__ b1, const float* __restrict__ b2,
    const float* __restrict__ gate, const float* __restrict__ tf,
    const float* __restrict__ proj_w, const float* __restrict__ proj_b,
    const float* __restrict__ pos, const int* __restrict__ wsI,
    float* __restrict__ wsP, ushort_t* __restrict__ pwP, float* __restrict__ pb) {
  int gid = blockIdx.x * 256 + threadIdx.x;
  if (gid < 6144) {
    int s = gid / 768, e = gid - s * 768;
    int base = (s >> 1) * 8 + wsI[s];
    float v;
    if (e < 128) v = ln_s[base * 128 + e];
    else if (e < 256) v = ln_b[base * 128 + e - 128];
    else if (e < 512) v = b1[base * 256 + e - 256];
    else if (e < 640) v = b2[base * 128 + e - 512];
    else { int d = e - 640; v = tf[d] * (1.0f / (1.0f + __expf(-gate[base * 128 + d]))); }
    wsP[gid] = v;
  } else if (gid < 10240) {
    int e = gid - 6144;
    int j = e & 7, ln = (e >> 3) & 63, nt = e >> 9;
    int k = (ln >> 4) * 8 + j, n = nt * 16 + (ln & 15);
    pwP[e] = f2bf(proj_w[k * 128 + n]);
  } else if (gid < 10368) {
    int d = gid - 10240;
    pb[d] = proj_b[d] + pos[d];
  }
}

// ---------------------------------------------------------------------------
// Kernel W: pack selected w1/w2 blocks into B-fragment bf16 layout.
// w1P[s]: [nt16][ks4][lane64][j8] = w1[k=ks*32+(lane>>4)*8+j][n=nt*16+(lane&15)]
// w2P[s]: [nt8 ][ks8][lane64][j8] = w2[k..][n..]
// ---------------------------------------------------------------------------
__global__ __launch_bounds__(256) void uv6_weights(
    const float* __restrict__ w1, const float* __restrict__ w2,
    const int* __restrict__ wsI, ushort_t* __restrict__ w1P,
    ushort_t* __restrict__ w2P) {
  int gid = blockIdx.x * 256 + threadIdx.x;  // < 524288
  int s = gid >> 16, e = gid & 65535;
  int base = (s >> 1) * 8 + wsI[s];
  if (e < 32768) {
    int j = e & 7, ln = (e >> 3) & 63, ks = (e >> 9) & 3, nt = e >> 11;
    int k = ks * 32 + (ln >> 4) * 8 + j;
    int n = nt * 16 + (ln & 15);
    w1P[s * 32768 + e] = f2bf(w1[(base * 128 + k) * 256 + n]);
  } else {
    int e2 = e - 32768;
    int j = e2 & 7, ln = (e2 >> 3) & 63, ks = (e2 >> 9) & 7, nt = e2 >> 12;
    int k = ks * 32 + (ln >> 4) * 8 + j;
    int n = nt * 16 + (ln & 15);
    w2P[s * 32768 + e2] = f2bf(w2[(base * 256 + k) * 128 + n]);
  }
}

// ---------------------------------------------------------------------------
// Kernel B: the batch. 1024 blocks x 256 thr (4 waves). 128 rows/block.
// h fp32 in LDS; hn/z1 round-trip via padded fragment buffer (520 elem/group
// -> conflict-free b128 A-frag reads). Waves split N: each weight fragment
// read exactly once per block-stage from L2.
// ---------------------------------------------------------------------------
__global__ __launch_bounds__(256, 1) void uv6_main(
    const float* __restrict__ x, const float* __restrict__ cls_w,
    const float* __restrict__ cls_b, const float* __restrict__ wsP,
    const float* __restrict__ pb, const ushort_t* __restrict__ pwP,
    const ushort_t* __restrict__ w1P, const ushort_t* __restrict__ w2P,
    float* __restrict__ out) {
  __shared__ float hbuf[TBROWS * LDS_HSTR];   // 66560 B
  __shared__ ushort_t frag[64 * 520];         // 66560 B (xP/hnP/z1P, phase-unioned)

  const int tid = threadIdx.x;
  const int w = tid >> 6, lane = tid & 63, q = lane >> 4, m0 = lane & 15;
  const int r = tid >> 1, half = tid & 1;     // row / col-half ownership
  const int rt_r = r >> 4, m_r = r & 15;
  const long rowbase = (long)blockIdx.x * TBROWS;

  // ---- phase 0: x tile -> A-fragments (bf16) ----
  {
    const float* xr = x + (rowbase + r) * 32 + half * 16;
    float xv[16];
#pragma unroll
    for (int i = 0; i < 4; ++i) ((float4*)xv)[i] = ((const float4*)xr)[i];
#pragma unroll
    for (int g = 0; g < 2; ++g) {
      s16x8 tv;
#pragma unroll
      for (int j = 0; j < 8; ++j) tv[j] = (short)f2bf(xv[g * 8 + j]);
      int kq = half * 2 + g;  // quad = k>>3
      *(s16x8*)&frag[rt_r * 520 + (kq * 16 + m_r) * 8] = tv;
    }
  }
  __syncthreads();

  // ---- projection: h = x @ proj_w + (proj_b + pos), via MFMA (K=32) ----
  {
    f32x4 acc[8][2];
    s16x8 bfr[2];
#pragma unroll
    for (int u = 0; u < 2; ++u) {
      int nt = w + 4 * u;
      bfr[u] = *(const s16x8*)(pwP + (nt * 64 + lane) * 8);
      float bv = pb[nt * 16 + m0];
#pragma unroll
      for (int rt = 0; rt < 8; ++rt) acc[rt][u] = (f32x4){bv, bv, bv, bv};
    }
#pragma unroll
    for (int rt = 0; rt < 8; ++rt) {
      s16x8 af = *(const s16x8*)&frag[rt * 520 + lane * 8];
      acc[rt][0] = __builtin_amdgcn_mfma_f32_16x16x32_bf16(af, bfr[0], acc[rt][0], 0, 0, 0);
      acc[rt][1] = __builtin_amdgcn_mfma_f32_16x16x32_bf16(af, bfr[1], acc[rt][1], 0, 0, 0);
    }
#pragma unroll
    for (int rt = 0; rt < 8; ++rt)
#pragma unroll
      for (int u = 0; u < 2; ++u) {
        int col = (w + 4 * u) * 16 + m0;
#pragma unroll
        for (int reg = 0; reg < 4; ++reg) {
          int row = rt * 16 + 4 * q + reg;  // C-layout: row = quad*4+reg
          hbuf[row * LDS_HSTR + col] = acc[rt][u][reg];
        }
      }
  }
  __syncthreads();

  float* outH = out + (size_t)BATCH * 2;

  // ---- 8 FFN block stages ----
  for (int s = 0; s < 8; ++s) {
    const float* prm = wsP + s * 768;
    const ushort_t* w1s = w1P + s * 32768;
    const ushort_t* w2s = w2P + s * 32768;

    // -- LayerNorm + pack hn into A-frag layout --
    {
      const float* hr = hbuf + r * LDS_HSTR + half * 64;
      float hv[64];
      float sum = 0.0f, ssq = 0.0f;
#pragma unroll
      for (int i = 0; i < 64; i += 2) {
        float2 v = *(const float2*)(hr + i);
        hv[i] = v.x; hv[i + 1] = v.y;
        sum += v.x + v.y;
        ssq += v.x * v.x + v.y * v.y;
      }
      sum += __shfl_xor(sum, 1);
      ssq += __shfl_xor(ssq, 1);
      float mu = sum * (1.0f / 128.0f);
      float rstd = rsqrtf(ssq * (1.0f / 128.0f) - mu * mu + 1e-5f);
      const float* lns = prm + half * 64;
      const float* lnb = prm + 128 + half * 64;
#pragma unroll
      for (int g = 0; g < 8; ++g) {
        s16x8 tv;
#pragma unroll
        for (int j = 0; j < 8; ++j) {
          float hnv = (hv[g * 8 + j] - mu) * rstd * lns[g * 8 + j] + lnb[g * 8 + j];
          tv[j] = (short)f2bf(hnv);
        }
        int kglob = half * 64 + g * 8;
        int kb = kglob >> 5, qq = (kglob >> 3) & 3;
        *(s16x8*)&frag[(rt_r * 4 + kb) * 520 + (qq * 16 + m_r) * 8] = tv;
      }
    }
    __syncthreads();

    // -- matmul1: z1 = hn @ w1 + b1 (wave w owns nt {w,w+4,w+8,w+12}) --
    f32x4 a1[8][4];
    {
      s16x8 bfr[4][4];
#pragma unroll
      for (int ni = 0; ni < 4; ++ni) {
        int nt = w + ni * 4;
#pragma unroll
        for (int ks = 0; ks < 4; ++ks)
          bfr[ni][ks] = *(const s16x8*)(w1s + ((nt * 4 + ks) * 64 + lane) * 8);
        float bv = prm[256 + nt * 16 + m0];
#pragma unroll
        for (int rt = 0; rt < 8; ++rt) a1[rt][ni] = (f32x4){bv, bv, bv, bv};
      }
#pragma unroll
      for (int rt = 0; rt < 8; ++rt) {
        s16x8 af[4];
#pragma unroll
        for (int ks = 0; ks < 4; ++ks)
          af[ks] = *(const s16x8*)&frag[(rt * 4 + ks) * 520 + lane * 8];
#pragma unroll
        for (int ni = 0; ni < 4; ++ni)
#pragma unroll
          for (int ks = 0; ks < 4; ++ks)
            a1[rt][ni] = __builtin_amdgcn_mfma_f32_16x16x32_bf16(af[ks], bfr[ni][ks], a1[rt][ni], 0, 0, 0);
      }
    }
    __syncthreads();  // all waves finished reading hnP

    // -- gelu + scatter z1 into matmul2 A-frag layout --
    {
#pragma unroll
      for (int ni = 0; ni < 4; ++ni) {
        int n = (w + ni * 4) * 16 + m0;  // z1 column = matmul2 k
        int kb = n >> 5, qq = (n >> 3) & 3, j = n & 7;
#pragma unroll
        for (int rt = 0; rt < 8; ++rt)
#pragma unroll
          for (int reg = 0; reg < 4; ++reg) {
            float g = geluf(a1[rt][ni][reg]);
            frag[(rt * 8 + kb) * 520 + (qq * 16 + 4 * q + reg) * 8 + j] = f2bf(g);
          }
      }
    }
    __syncthreads();

    // -- matmul2: z2 = z1 @ w2 + b2 (wave w owns nt2 {w,w+4}) --
    f32x4 a2[8][2];
    {
      s16x8 bfr[2][8];
#pragma unroll
      for (int ni = 0; ni < 2; ++ni) {
        int nt = w + ni * 4;
#pragma unroll
        for (int ks = 0; ks < 8; ++ks)
          bfr[ni][ks] = *(const s16x8*)(w2s + ((nt * 8 + ks) * 64 + lane) * 8);
        float bv = prm[512 + nt * 16 + m0];
#pragma unroll
        for (int rt = 0; rt < 8; ++rt) a2[rt][ni] = (f32x4){bv, bv, bv, bv};
      }
#pragma unroll
      for (int rt = 0; rt < 8; ++rt) {
        s16x8 af[8];
#pragma unroll
        for (int ks = 0; ks < 8; ++ks)
          af[ks] = *(const s16x8*)&frag[(rt * 8 + ks) * 520 + lane * 8];
#pragma unroll
        for (int ni = 0; ni < 2; ++ni)
#pragma unroll
          for (int ks = 0; ks < 8; ++ks)
            a2[rt][ni] = __builtin_amdgcn_mfma_f32_16x16x32_bf16(af[ks], bfr[ni][ks], a2[rt][ni], 0, 0, 0);
      }
    }

    // -- epilogue: z *= (1+te); h += 0.5*z (LDS RMW, 2-way free banks) --
    {
#pragma unroll
      for (int ni = 0; ni < 2; ++ni) {
        int col = (w + ni * 4) * 16 + m0;
        float sc = 0.5f * (1.0f + prm[640 + col]);
#pragma unroll
        for (int rt = 0; rt < 8; ++rt)
#pragma unroll
          for (int reg = 0; reg < 4; ++reg) {
            int row = rt * 16 + 4 * q + reg;
            hbuf[row * LDS_HSTR + col] += sc * a2[rt][ni][reg];
          }
      }
    }
    __syncthreads();
  }

  // ---- output: logits = h @ cls_w + cls_b ; raw h ----
  {
    const float* hr = hbuf + r * LDS_HSTR + half * 64;
    const long grow = rowbase + r;
    float* oh = outH + grow * 128 + half * 64;
    float l0 = 0.0f, l1 = 0.0f;
#pragma unroll
    for (int i = 0; i < 64; i += 4) {
      float2 va = *(const float2*)(hr + i);
      float2 vb = *(const float2*)(hr + i + 2);
      float4 vv = {va.x, va.y, vb.x, vb.y};
      *(float4*)(oh + i) = vv;
      int c = (half * 64 + i) * 2;
      l0 += va.x * cls_w[c] + va.y * cls_w[c + 2] + vb.x * cls_w[c + 4] + vb.y * cls_w[c + 6];
      l1 += va.x * cls_w[c + 1] + va.y * cls_w[c + 3] + vb.x * cls_w[c + 5] + vb.y * cls_w[c + 7];
    }
    l0 += __shfl_xor(l0, 1);
    l1 += __shfl_xor(l1, 1);
    if (half == 0) {
      float2 lg = {l0 + cls_b[0], l1 + cls_b[1]};
      *(float2*)(out + grow * 2) = lg;
    }
  }
}

// ---------------------------------------------------------------------------
extern "C" void kernel_launch(void* const* d_in, const int* in_sizes, int n_in,
                              void* d_out, int out_size, void* d_ws, size_t ws_size,
                              hipStream_t stream) {
  (void)in_sizes; (void)n_in; (void)out_size; (void)ws_size;
  const float* x      = (const float*)d_in[0];
  const float* proj_w = (const float*)d_in[1];
  const float* proj_b = (const float*)d_in[2];
  const float* pos    = (const float*)d_in[3];
  const float* sel_w  = (const float*)d_in[4];
  const float* sel_b  = (const float*)d_in[5];
  const float* ln_s   = (const float*)d_in[6];
  const float* ln_b   = (const float*)d_in[7];
  const float* w1     = (const float*)d_in[8];
  const float* b1     = (const float*)d_in[9];
  const float* w2     = (const float*)d_in[10];
  const float* b2     = (const float*)d_in[11];
  const float* gate   = (const float*)d_in[12];
  const float* cls_w  = (const float*)d_in[13];
  const float* cls_b  = (const float*)d_in[14];
  const float* tf     = (const float*)d_in[15];

  char* ws = (char*)d_ws;
  int* wsI        = (int*)(ws + WS_IDX);
  float* wsP      = (float*)(ws + WS_PRM);
  float* pb       = (float*)(ws + WS_PB);
  ushort_t* pwP   = (ushort_t*)(ws + WS_PW);
  ushort_t* w1P   = (ushort_t*)(ws + WS_W1);
  ushort_t* w2P   = (ushort_t*)(ws + WS_W2);
  float* outF     = (float*)d_out;

  uv6_select<<<1, 256, 0, stream>>>(x, proj_w, proj_b, pos, sel_w, sel_b, ln_s,
                                    ln_b, w1, b1, w2, b2, gate, tf, wsI);
  uv6_params<<<41, 256, 0, stream>>>(ln_s, ln_b, b1, b2, gate, tf, proj_w,
                                     proj_b, pos, wsI, wsP, pwP, pb);
  uv6_weights<<<2048, 256, 0, stream>>>(w1, w2, wsI, w1P, w2P);
  uv6_main<<<BATCH / TBROWS, 256, 0, stream>>>(x, cls_w, cls_b, wsP, pb, pwP,
                                               w1P, w2P, outF);
}

// Round 2
// 503.878 us; speedup vs baseline: 1.3717x; 1.3717x over previous
//
#include <hip/hip_runtime.h>

// ---------------------------------------------------------------------------
// UltimateV6 r2: top-k depends only on batch row 0 -> tiny select kernel,
// then batch is a static chain of 8 FFN blocks on bf16 MFMA.
// r2 changes: TBROWS 128->32 (LDS 133KB->33KB) -> 4 blocks/CU, 4 waves/SIMD
// (was 1); launch_bounds(256,4); flat coalesced h write; select unroll 16;
// params+weights packing merged into one launch.
// ---------------------------------------------------------------------------

typedef __attribute__((ext_vector_type(8))) short s16x8;
typedef __attribute__((ext_vector_type(4))) float f32x4;
typedef unsigned short ushort_t;

#define BATCH 131072
#define TBROWS 32
#define HSTR 130   // h row stride in floats: %32==2 -> 2-way (free) conflicts on epilogue

// ws layout (bytes)
#define WS_IDX 0        // int[8]
#define WS_PRM 64       // float[8][768]: ln_s128 ln_b128 b1x256 b2x128 te128
#define WS_PB  24640    // float[128]: proj_b + pos
#define WS_PW  25152    // ushort[4096]: proj_w frag-packed bf16
#define WS_W1  33344    // ushort[8][32768]
#define WS_W2  557632   // ushort[8][32768]

__device__ inline ushort_t f2bf(float f) {
  unsigned u = __float_as_uint(f);
  u += 0x7fffu + ((u >> 16) & 1u);
  return (ushort_t)(u >> 16);
}

// gelu ~= x * sigmoid(1.702 x); decorrelated through random w2, 0.5 residual.
__device__ inline float geluf(float v) {
  float e = __builtin_amdgcn_exp2f(-2.4554670f * v);
  return v * __builtin_amdgcn_rcpf(1.0f + e);
}

// ---------------------------------------------------------------------------
// Kernel A: row-0 trajectory in exact fp32 (erff), emit 8 selected indices.
// unroll 16 -> 16 outstanding global loads per thread (was 8).
// ---------------------------------------------------------------------------
__global__ __launch_bounds__(256) void uv6_select(
    const float* __restrict__ x, const float* __restrict__ proj_w,
    const float* __restrict__ proj_b, const float* __restrict__ pos,
    const float* __restrict__ sel_w, const float* __restrict__ sel_b,
    const float* __restrict__ ln_s, const float* __restrict__ ln_b,
    const float* __restrict__ w1, const float* __restrict__ b1,
    const float* __restrict__ w2, const float* __restrict__ b2,
    const float* __restrict__ gate, const float* __restrict__ tf,
    int* __restrict__ wsI) {
  __shared__ float h0[128], hn[128], z1[256], red[256], adjs[8];
  __shared__ int top[2];
  __shared__ float muS, rstdS;
  int t = threadIdx.x;
  if (t < 128) {
    float a = proj_b[t] + pos[t];
#pragma unroll 8
    for (int f = 0; f < 32; ++f) a += x[f] * proj_w[f * 128 + t];
    h0[t] = a;
  }
  __syncthreads();
  for (int l = 0; l < 4; ++l) {
    if (t < 8) {
      float sc = sel_b[l * 8 + t];
#pragma unroll 16
      for (int d = 0; d < 128; ++d) sc += h0[d] * sel_w[(l * 128 + d) * 8 + t];
      sc = 1.0f / (1.0f + __expf(-sc));
      adjs[t] = sc * 0.6f + 0.2f;  // priority 0.5 * 0.4
    }
    __syncthreads();
    if (t == 0) {
      int i0 = 0; float v0 = adjs[0];
      for (int j = 1; j < 8; ++j) if (adjs[j] > v0) { v0 = adjs[j]; i0 = j; }
      int i1 = -1; float v1 = -1e30f;
      for (int j = 0; j < 8; ++j) if (j != i0 && adjs[j] > v1) { v1 = adjs[j]; i1 = j; }
      top[0] = i0; top[1] = i1;
      wsI[2 * l] = i0; wsI[2 * l + 1] = i1;
    }
    __syncthreads();
    for (int kk = 0; kk < 2; ++kk) {
      int base = l * 8 + top[kk];
      red[t] = (t < 128) ? h0[t] : 0.0f;
      __syncthreads();
      for (int off = 128; off > 0; off >>= 1) {
        if (t < off) red[t] += red[t + off];
        __syncthreads();
      }
      if (t == 0) muS = red[0] * (1.0f / 128.0f);
      __syncthreads();
      float mu = muS;
      red[t] = 0.0f;
      if (t < 128) { float d = h0[t] - mu; red[t] = d * d; }
      __syncthreads();
      for (int off = 128; off > 0; off >>= 1) {
        if (t < off) red[t] += red[t + off];
        __syncthreads();
      }
      if (t == 0) rstdS = rsqrtf(red[0] * (1.0f / 128.0f) + 1e-5f);
      __syncthreads();
      if (t < 128)
        hn[t] = (h0[t] - mu) * rstdS * ln_s[base * 128 + t] + ln_b[base * 128 + t];
      __syncthreads();
      {
        float a = b1[base * 256 + t];
#pragma unroll 16
        for (int d = 0; d < 128; ++d) a += hn[d] * w1[(base * 128 + d) * 256 + t];
        a = 0.5f * a * (1.0f + erff(a * 0.70710678118f));  // exact gelu
        z1[t] = a;
      }
      __syncthreads();
      {
        int d = t & 127, part = t >> 7;
        float a = 0.0f;
#pragma unroll 16
        for (int n = part * 128; n < part * 128 + 128; ++n)
          a += z1[n] * w2[(base * 256 + n) * 128 + d];
        red[t] = a;
      }
      __syncthreads();
      if (t < 128) {
        float z2 = red[t] + red[t + 128] + b2[base * 128 + t];
        float te = tf[t] * (1.0f / (1.0f + __expf(-gate[base * 128 + t])));
        h0[t] += 0.5f * z2 * (1.0f + te);
      }
      __syncthreads();
    }
  }
}

// ---------------------------------------------------------------------------
// Kernel P (merged): blocks 0..2047 pack w1/w2 B-fragments; blocks 2048..2088
// pack per-stage params + proj_w fragments + proj_b+pos.
// w1P[s]: [nt16][ks4][lane64][j8] = w1[k=ks*32+(lane>>4)*8+j][n=nt*16+(lane&15)]
// w2P[s]: [nt8 ][ks8][lane64][j8]
// ---------------------------------------------------------------------------
__global__ __launch_bounds__(256) void uv6_pack(
    const float* __restrict__ w1, const float* __restrict__ w2,
    const float* __restrict__ ln_s, const float* __restrict__ ln_b,
    const float* __restrict__ b1, const float* __restrict__ b2,
    const float* __restrict__ gate, const float* __restrict__ tf,
    const float* __restrict__ proj_w, const float* __restrict__ proj_b,
    const float* __restrict__ pos, const int* __restrict__ wsI,
    ushort_t* __restrict__ w1P, ushort_t* __restrict__ w2P,
    float* __restrict__ wsP, ushort_t* __restrict__ pwP,
    float* __restrict__ pb) {
  if (blockIdx.x < 2048) {
    int gid = blockIdx.x * 256 + threadIdx.x;  // < 524288
    int s = gid >> 16, e = gid & 65535;
    int base = (s >> 1) * 8 + wsI[s];
    if (e < 32768) {
      int j = e & 7, ln = (e >> 3) & 63, ks = (e >> 9) & 3, nt = e >> 11;
      int k = ks * 32 + (ln >> 4) * 8 + j;
      int n = nt * 16 + (ln & 15);
      w1P[s * 32768 + e] = f2bf(w1[(base * 128 + k) * 256 + n]);
    } else {
      int e2 = e - 32768;
      int j = e2 & 7, ln = (e2 >> 3) & 63, ks = (e2 >> 9) & 7, nt = e2 >> 12;
      int k = ks * 32 + (ln >> 4) * 8 + j;
      int n = nt * 16 + (ln & 15);
      w2P[s * 32768 + e2] = f2bf(w2[(base * 256 + k) * 128 + n]);
    }
    return;
  }
  int gid = (blockIdx.x - 2048) * 256 + threadIdx.x;
  if (gid < 6144) {
    int s = gid / 768, e = gid - s * 768;
    int base = (s >> 1) * 8 + wsI[s];
    float v;
    if (e < 128) v = ln_s[base * 128 + e];
    else if (e < 256) v = ln_b[base * 128 + e - 128];
    else if (e < 512) v = b1[base * 256 + e - 256];
    else if (e < 640) v = b2[base * 128 + e - 512];
    else { int d = e - 640; v = tf[d] * (1.0f / (1.0f + __expf(-gate[base * 128 + d]))); }
    wsP[gid] = v;
  } else if (gid < 10240) {
    int e = gid - 6144;
    int j = e & 7, ln = (e >> 3) & 63, nt = e >> 9;
    int k = (ln >> 4) * 8 + j, n = nt * 16 + (ln & 15);
    pwP[e] = f2bf(proj_w[k * 128 + n]);
  } else if (gid < 10368) {
    int d = gid - 10240;
    pb[d] = proj_b[d] + pos[d];
  }
}

// ---------------------------------------------------------------------------
// Kernel B: the batch. 4096 blocks x 256 thr (4 waves), 32 rows/block.
// LDS 33280 B -> 4 blocks/CU resident = 4 waves/SIMD (was 1). Wave tile:
// 32 rows x 64 cols -> acc <= 32 VGPR per matmul, fits the 128-VGPR cap.
// ---------------------------------------------------------------------------
__global__ __launch_bounds__(256, 4) void uv6_main(
    const float* __restrict__ x, const float* __restrict__ cls_w,
    const float* __restrict__ cls_b, const float* __restrict__ wsP,
    const float* __restrict__ pb, const ushort_t* __restrict__ pwP,
    const ushort_t* __restrict__ w1P, const ushort_t* __restrict__ w2P,
    float* __restrict__ out) {
  __shared__ float hbuf[TBROWS * HSTR];    // 16640 B
  __shared__ ushort_t frag[16 * 520];      // 16640 B (xP/hnP/z1P phase-unioned)

  const int tid = threadIdx.x;
  const int w = tid >> 6, lane = tid & 63, q = lane >> 4, m0 = lane & 15;
  const int r = tid >> 3, p = tid & 7;     // row / col-part (16 cols each)
  const int rt_r = r >> 4, m_r = r & 15;
  const long rowbase = (long)blockIdx.x * TBROWS;

  // ---- phase 0: x tile [32 rows x 32 cols] -> A-fragments (bf16) ----
  {
    float4 xv = *(const float4*)(x + (rowbase + r) * 32 + p * 4);
    ushort_t u0 = f2bf(xv.x), u1 = f2bf(xv.y), u2 = f2bf(xv.z), u3 = f2bf(xv.w);
    // k = 4p..4p+3 -> quad = p>>1, j = (p&1)*4 + i
    ushort_t* dst = &frag[rt_r * 520 + ((p >> 1) * 16 + m_r) * 8 + (p & 1) * 4];
    dst[0] = u0; dst[1] = u1; dst[2] = u2; dst[3] = u3;
  }
  __syncthreads();

  // ---- projection: h = x @ proj_w + (proj_b+pos) ; wave w: nt {w, w+4} ----
  {
    f32x4 acc[2][2];
    s16x8 bfr[2];
#pragma unroll
    for (int u = 0; u < 2; ++u) {
      int nt = w + 4 * u;
      bfr[u] = *(const s16x8*)(pwP + (nt * 64 + lane) * 8);
      float bv = pb[nt * 16 + m0];
#pragma unroll
      for (int rt = 0; rt < 2; ++rt) acc[rt][u] = (f32x4){bv, bv, bv, bv};
    }
#pragma unroll
    for (int rt = 0; rt < 2; ++rt) {
      s16x8 af = *(const s16x8*)&frag[rt * 520 + lane * 8];
      acc[rt][0] = __builtin_amdgcn_mfma_f32_16x16x32_bf16(af, bfr[0], acc[rt][0], 0, 0, 0);
      acc[rt][1] = __builtin_amdgcn_mfma_f32_16x16x32_bf16(af, bfr[1], acc[rt][1], 0, 0, 0);
    }
#pragma unroll
    for (int rt = 0; rt < 2; ++rt)
#pragma unroll
      for (int u = 0; u < 2; ++u) {
        int col = (w + 4 * u) * 16 + m0;
#pragma unroll
        for (int reg = 0; reg < 4; ++reg)
          hbuf[(rt * 16 + 4 * q + reg) * HSTR + col] = acc[rt][u][reg];
      }
  }
  __syncthreads();

  float* outH = out + (size_t)BATCH * 2;

  // ---- 8 FFN block stages ----
  for (int s = 0; s < 8; ++s) {
    const float* prm = wsP + s * 768;
    const ushort_t* w1s = w1P + s * 32768;
    const ushort_t* w2s = w2P + s * 32768;

    // -- LayerNorm (8 lanes/row) + pack hn into A-frag layout --
    {
      const float* hr = hbuf + r * HSTR + p * 16;
      float hv[16];
      float sum = 0.0f, ssq = 0.0f;
#pragma unroll
      for (int i = 0; i < 16; i += 2) {
        float2 v = *(const float2*)(hr + i);
        hv[i] = v.x; hv[i + 1] = v.y;
        sum += v.x + v.y;
        ssq += v.x * v.x + v.y * v.y;
      }
      sum += __shfl_xor(sum, 1); ssq += __shfl_xor(ssq, 1);
      sum += __shfl_xor(sum, 2); ssq += __shfl_xor(ssq, 2);
      sum += __shfl_xor(sum, 4); ssq += __shfl_xor(ssq, 4);
      float mu = sum * (1.0f / 128.0f);
      float rstd = rsqrtf(ssq * (1.0f / 128.0f) - mu * mu + 1e-5f);
      const float* lns = prm + p * 16;
      const float* lnb = prm + 128 + p * 16;
#pragma unroll
      for (int g = 0; g < 2; ++g) {
        s16x8 tv;
#pragma unroll
        for (int j = 0; j < 8; ++j) {
          float hnv = (hv[g * 8 + j] - mu) * rstd * lns[g * 8 + j] + lnb[g * 8 + j];
          tv[j] = (short)f2bf(hnv);
        }
        int kb = p >> 1, qq = (2 * p + g) & 3;
        *(s16x8*)&frag[(rt_r * 4 + kb) * 520 + (qq * 16 + m_r) * 8] = tv;
      }
    }
    __syncthreads();

    // -- matmul1: z1 = hn @ w1 + b1 (wave w owns nt {w,w+4,w+8,w+12}) --
    f32x4 a1[2][4];
    {
#pragma unroll
      for (int ni = 0; ni < 4; ++ni) {
        float bv = prm[256 + (w + ni * 4) * 16 + m0];
        a1[0][ni] = (f32x4){bv, bv, bv, bv};
        a1[1][ni] = (f32x4){bv, bv, bv, bv};
      }
#pragma unroll
      for (int ks = 0; ks < 4; ++ks) {
        s16x8 af0 = *(const s16x8*)&frag[ks * 520 + lane * 8];
        s16x8 af1 = *(const s16x8*)&frag[(4 + ks) * 520 + lane * 8];
#pragma unroll
        for (int ni = 0; ni < 4; ++ni) {
          int nt = w + ni * 4;
          s16x8 bf = *(const s16x8*)(w1s + ((nt * 4 + ks) * 64 + lane) * 8);
          a1[0][ni] = __builtin_amdgcn_mfma_f32_16x16x32_bf16(af0, bf, a1[0][ni], 0, 0, 0);
          a1[1][ni] = __builtin_amdgcn_mfma_f32_16x16x32_bf16(af1, bf, a1[1][ni], 0, 0, 0);
        }
      }
    }
    __syncthreads();  // all waves done reading hn frags

    // -- gelu + scatter z1 into matmul2 A-frag layout --
    {
#pragma unroll
      for (int ni = 0; ni < 4; ++ni) {
        int n = (w + ni * 4) * 16 + m0;  // z1 column = matmul2 k
        int kb = n >> 5, qq = (n >> 3) & 3, j = n & 7;
#pragma unroll
        for (int rt = 0; rt < 2; ++rt)
#pragma unroll
          for (int reg = 0; reg < 4; ++reg)
            frag[(rt * 8 + kb) * 520 + (qq * 16 + 4 * q + reg) * 8 + j] =
                f2bf(geluf(a1[rt][ni][reg]));
      }
    }
    __syncthreads();

    // -- matmul2: z2 = z1 @ w2 + b2 (wave w owns nt2 {w, w+4}) --
    f32x4 a2[2][2];
    {
#pragma unroll
      for (int ni = 0; ni < 2; ++ni) {
        float bv = prm[512 + (w + ni * 4) * 16 + m0];
        a2[0][ni] = (f32x4){bv, bv, bv, bv};
        a2[1][ni] = (f32x4){bv, bv, bv, bv};
      }
#pragma unroll
      for (int ks = 0; ks < 8; ++ks) {
        s16x8 af0 = *(const s16x8*)&frag[ks * 520 + lane * 8];
        s16x8 af1 = *(const s16x8*)&frag[(8 + ks) * 520 + lane * 8];
#pragma unroll
        for (int ni = 0; ni < 2; ++ni) {
          int nt = w + ni * 4;
          s16x8 bf = *(const s16x8*)(w2s + ((nt * 8 + ks) * 64 + lane) * 8);
          a2[0][ni] = __builtin_amdgcn_mfma_f32_16x16x32_bf16(af0, bf, a2[0][ni], 0, 0, 0);
          a2[1][ni] = __builtin_amdgcn_mfma_f32_16x16x32_bf16(af1, bf, a2[1][ni], 0, 0, 0);
        }
      }
    }

    // -- epilogue: h += 0.5*(1+te)*z2 (LDS RMW, 2-way free banks) --
    {
#pragma unroll
      for (int ni = 0; ni < 2; ++ni) {
        int col = (w + ni * 4) * 16 + m0;
        float sc = 0.5f * (1.0f + prm[640 + col]);
#pragma unroll
        for (int rt = 0; rt < 2; ++rt)
#pragma unroll
          for (int reg = 0; reg < 4; ++reg)
            hbuf[(rt * 16 + 4 * q + reg) * HSTR + col] += sc * a2[rt][ni][reg];
      }
    }
    __syncthreads();
  }

  // ---- h write-out: flat, lane-contiguous float4 (perfect coalescing) ----
#pragma unroll
  for (int it = 0; it < 4; ++it) {
    int p4 = it * 256 + tid;
    int row = p4 >> 5, c = (p4 & 31) * 4;
    float2 v0 = *(const float2*)(hbuf + row * HSTR + c);
    float2 v1 = *(const float2*)(hbuf + row * HSTR + c + 2);
    float4 o = {v0.x, v0.y, v1.x, v1.y};
    *(float4*)(outH + rowbase * 128 + p4 * 4) = o;
  }

  // ---- logits = h @ cls_w + cls_b (8 lanes/row, xor-reduce) ----
  {
    const float* hr = hbuf + r * HSTR + p * 16;
    float l0 = 0.0f, l1 = 0.0f;
#pragma unroll
    for (int i = 0; i < 16; i += 2) {
      float2 v = *(const float2*)(hr + i);
      int c = (p * 16 + i) * 2;
      l0 += v.x * cls_w[c] + v.y * cls_w[c + 2];
      l1 += v.x * cls_w[c + 1] + v.y * cls_w[c + 3];
    }
    l0 += __shfl_xor(l0, 1); l1 += __shfl_xor(l1, 1);
    l0 += __shfl_xor(l0, 2); l1 += __shfl_xor(l1, 2);
    l0 += __shfl_xor(l0, 4); l1 += __shfl_xor(l1, 4);
    if (p == 0) {
      float2 lg = {l0 + cls_b[0], l1 + cls_b[1]};
      *(float2*)(out + (rowbase + r) * 2) = lg;
    }
  }
}

// ---------------------------------------------------------------------------
extern "C" void kernel_launch(void* const* d_in, const int* in_sizes, int n_in,
                              void* d_out, int out_size, void* d_ws, size_t ws_size,
                              hipStream_t stream) {
  (void)in_sizes; (void)n_in; (void)out_size; (void)ws_size;
  const float* x      = (const float*)d_in[0];
  const float* proj_w = (const float*)d_in[1];
  const float* proj_b = (const float*)d_in[2];
  const float* pos    = (const float*)d_in[3];
  const float* sel_w  = (const float*)d_in[4];
  const float* sel_b  = (const float*)d_in[5];
  const float* ln_s   = (const float*)d_in[6];
  const float* ln_b   = (const float*)d_in[7];
  const float* w1     = (const float*)d_in[8];
  const float* b1     = (const float*)d_in[9];
  const float* w2     = (const float*)d_in[10];
  const float* b2     = (const float*)d_in[11];
  const float* gate   = (const float*)d_in[12];
  const float* cls_w  = (const float*)d_in[13];
  const float* cls_b  = (const float*)d_in[14];
  const float* tf     = (const float*)d_in[15];

  char* ws = (char*)d_ws;
  int* wsI        = (int*)(ws + WS_IDX);
  float* wsP      = (float*)(ws + WS_PRM);
  float* pb       = (float*)(ws + WS_PB);
  ushort_t* pwP   = (ushort_t*)(ws + WS_PW);
  ushort_t* w1P   = (ushort_t*)(ws + WS_W1);
  ushort_t* w2P   = (ushort_t*)(ws + WS_W2);
  float* outF     = (float*)d_out;

  uv6_select<<<1, 256, 0, stream>>>(x, proj_w, proj_b, pos, sel_w, sel_b, ln_s,
                                    ln_b, w1, b1, w2, b2, gate, tf, wsI);
  uv6_pack<<<2089, 256, 0, stream>>>(w1, w2, ln_s, ln_b, b1, b2, gate, tf,
                                     proj_w, proj_b, pos, wsI, w1P, w2P, wsP,
                                     pwP, pb);
  uv6_main<<<BATCH / TBROWS, 256, 0, stream>>>(x, cls_w, cls_b, wsP, pb, pwP,
                                               w1P, w2P, outF);
}

// Round 3
// 454.749 us; speedup vs baseline: 1.5198x; 1.1080x over previous
//
#include <hip/hip_runtime.h>

// ---------------------------------------------------------------------------
// UltimateV6 r3: top-k depends only on batch row 0 -> tiny select kernel,
// then batch is a static chain of 8 FFN blocks on bf16 MFMA.
// r3: 1024-thr select w/ full weight prefetch (was 147us serial tail);
// HSTR 132 -> conflict-free b128 LN reads; ln/te folded into packed weights;
// perm-packed bf16 cvt; B-frag prefetch ahead of barriers.
// ---------------------------------------------------------------------------

typedef __attribute__((ext_vector_type(8))) short s16x8;
typedef __attribute__((ext_vector_type(4))) float f32x4;
typedef unsigned short ushort_t;

#define BATCH 131072
#define TBROWS 32
#define HSTR 132   // %4==0 -> aligned b128 rows; %32==4 -> spread banks

// ws layout (bytes)
#define WS_IDX 0        // int[8]
#define WS_PRM 64       // float[8][384]: c1'[256] c2'[128]
#define WS_PB  12352    // float[128]: proj_b + pos
#define WS_PW  12864    // ushort[4096]: proj_w frag-packed bf16
#define WS_W1  21056    // ushort[8][32768]  w1' = ln_s-folded
#define WS_W2  545344   // ushort[8][32768]  w2' = 0.5(1+te)-folded

__device__ inline ushort_t f2bf(float f) {         // RNE (cold paths)
  unsigned u = __float_as_uint(f);
  u += 0x7fffu + ((u >> 16) & 1u);
  return (ushort_t)(u >> 16);
}
__device__ inline ushort_t f2bf1(float f) {        // round-half-up, 2 ops
  return (ushort_t)((__float_as_uint(f) + 0x8000u) >> 16);
}
__device__ inline unsigned f2bf2(float lo, float hi) {  // 2 vals -> 1 u32, 3 ops
  unsigned a = __float_as_uint(lo) + 0x8000u;
  unsigned b = __float_as_uint(hi) + 0x8000u;
  return __builtin_amdgcn_perm(b, a, 0x07060302u);  // [b.hi16 : a.hi16]
}

// gelu ~= x * sigmoid(1.702 x)
__device__ inline float geluf(float v) {
  float e = __builtin_amdgcn_exp2f(-2.4554670f * v);
  return v * __builtin_amdgcn_rcpf(1.0f + e);
}

// ---------------------------------------------------------------------------
// Kernel A: row-0 trajectory, exact fp32 (erff). 1024 threads; per selection
// both weight matrices prefetched to registers (64 loads/thr, 256KB in
// flight) right after the block index is known; shfl-based reductions.
// ---------------------------------------------------------------------------
__global__ __launch_bounds__(1024) void uv6_select(
    const float* __restrict__ x, const float* __restrict__ proj_w,
    const float* __restrict__ proj_b, const float* __restrict__ pos,
    const float* __restrict__ sel_w, const float* __restrict__ sel_b,
    const float* __restrict__ ln_s, const float* __restrict__ ln_b,
    const float* __restrict__ w1, const float* __restrict__ b1,
    const float* __restrict__ w2, const float* __restrict__ b2,
    const float* __restrict__ gate, const float* __restrict__ tf,
    int* __restrict__ wsI) {
  __shared__ float h0[128], hn[128], z1[256];
  __shared__ float red[1024];
  __shared__ float wred[128];
  __shared__ float adjs[8];
  __shared__ int top[2];
  __shared__ float stat[2];
  const int t = threadIdx.x;
  const int lane = t & 63, wv = t >> 6;
  const int n1 = t & 255, dp1 = t >> 8;   // mm1 ownership
  const int n2 = t & 127, dp2 = t >> 7;   // mm2 ownership

  if (t < 128) {
    float a = proj_b[t] + pos[t];
#pragma unroll
    for (int f = 0; f < 32; ++f) a += x[f] * proj_w[f * 128 + t];
    h0[t] = a;
  }
  __syncthreads();

  for (int l = 0; l < 4; ++l) {
    // selector scores: thread (d = t>>3, j = t&7); shfl-reduce d within wave
    {
      float pp = h0[t >> 3] * sel_w[(l * 128 + (t >> 3)) * 8 + (t & 7)];
      pp += __shfl_xor(pp, 8);
      pp += __shfl_xor(pp, 16);
      pp += __shfl_xor(pp, 32);
      if (lane < 8) wred[wv * 8 + lane] = pp;
    }
    __syncthreads();
    if (t < 8) {
      float sc = sel_b[l * 8 + t];
#pragma unroll
      for (int v = 0; v < 16; ++v) sc += wred[v * 8 + t];
      sc = 1.0f / (1.0f + __expf(-sc));
      adjs[t] = sc * 0.6f + 0.2f;  // priority 0.5 * 0.4
    }
    __syncthreads();
    if (t == 0) {
      int i0 = 0; float v0 = adjs[0];
      for (int j = 1; j < 8; ++j) if (adjs[j] > v0) { v0 = adjs[j]; i0 = j; }
      int i1 = -1; float v1 = -1e30f;
      for (int j = 0; j < 8; ++j) if (j != i0 && adjs[j] > v1) { v1 = adjs[j]; i1 = j; }
      top[0] = i0; top[1] = i1;
      wsI[2 * l] = i0; wsI[2 * l + 1] = i1;
    }
    __syncthreads();
    for (int kk = 0; kk < 2; ++kk) {
      const int base = l * 8 + top[kk];
      // ---- prefetch both weight matrices into registers ----
      float w1v[32], w2v[32];
      const float* w1p = w1 + (base * 128 + dp1 * 32) * 256 + n1;
      const float* w2p = w2 + (base * 256 + dp2 * 32) * 128 + n2;
#pragma unroll
      for (int j = 0; j < 32; ++j) w1v[j] = w1p[j * 256];
#pragma unroll
      for (int j = 0; j < 32; ++j) w2v[j] = w2p[j * 128];
      // ---- LN stats (wave 0, shfl) ----
      if (t < 64) {
        float a = h0[t], b = h0[t + 64];
        float s2 = a + b, q2 = a * a + b * b;
        s2 += __shfl_xor(s2, 1);  q2 += __shfl_xor(q2, 1);
        s2 += __shfl_xor(s2, 2);  q2 += __shfl_xor(q2, 2);
        s2 += __shfl_xor(s2, 4);  q2 += __shfl_xor(q2, 4);
        s2 += __shfl_xor(s2, 8);  q2 += __shfl_xor(q2, 8);
        s2 += __shfl_xor(s2, 16); q2 += __shfl_xor(q2, 16);
        s2 += __shfl_xor(s2, 32); q2 += __shfl_xor(q2, 32);
        if (t == 0) {
          float mu = s2 * (1.0f / 128.0f);
          stat[0] = mu;
          stat[1] = rsqrtf(q2 * (1.0f / 128.0f) - mu * mu + 1e-5f);
        }
      }
      __syncthreads();
      if (t < 128)
        hn[t] = (h0[t] - stat[0]) * stat[1] * ln_s[base * 128 + t] + ln_b[base * 128 + t];
      __syncthreads();
      {
        float a = 0.0f;
#pragma unroll
        for (int j = 0; j < 32; ++j) a += hn[dp1 * 32 + j] * w1v[j];
        red[dp1 * 256 + n1] = a;
      }
      __syncthreads();
      if (t < 256) {
        float z = red[t] + red[256 + t] + red[512 + t] + red[768 + t] + b1[base * 256 + t];
        z1[t] = z * 0.5f * (1.0f + erff(z * 0.70710678118f));  // exact gelu
      }
      __syncthreads();
      {
        float a = 0.0f;
#pragma unroll
        for (int j = 0; j < 32; ++j) a += z1[dp2 * 32 + j] * w2v[j];
        red[dp2 * 128 + n2] = a;
      }
      __syncthreads();
      if (t < 128) {
        float z2 = b2[base * 128 + t];
#pragma unroll
        for (int v = 0; v < 8; ++v) z2 += red[v * 128 + t];
        float te = tf[t] * (1.0f / (1.0f + __expf(-gate[base * 128 + t])));
        h0[t] += 0.5f * z2 * (1.0f + te);
      }
      __syncthreads();
    }
  }
}

// ---------------------------------------------------------------------------
// Kernel P: blocks 0..2047 pack w1'(=ln_s-folded) / w2'(=0.5(1+te)-folded)
// B-fragments; blocks 2048..2055 compute c1'= b1 + ln_b@w1 and
// c2'= 0.5(1+te).b2; blocks 2056.. pack proj fragments + pb.
// ---------------------------------------------------------------------------
__global__ __launch_bounds__(256) void uv6_pack(
    const float* __restrict__ w1, const float* __restrict__ w2,
    const float* __restrict__ ln_s, const float* __restrict__ ln_b,
    const float* __restrict__ b1, const float* __restrict__ b2,
    const float* __restrict__ gate, const float* __restrict__ tf,
    const float* __restrict__ proj_w, const float* __restrict__ proj_b,
    const float* __restrict__ pos, const int* __restrict__ wsI,
    ushort_t* __restrict__ w1P, ushort_t* __restrict__ w2P,
    float* __restrict__ wsP, ushort_t* __restrict__ pwP,
    float* __restrict__ pb) {
  const int bx = blockIdx.x;
  if (bx < 2048) {
    int gid = bx * 256 + threadIdx.x;
    int s = gid >> 16, e = gid & 65535;
    int base = (s >> 1) * 8 + wsI[s];
    if (e < 32768) {
      int j = e & 7, ln = (e >> 3) & 63, ks = (e >> 9) & 3, nt = e >> 11;
      int k = ks * 32 + (ln >> 4) * 8 + j;
      int n = nt * 16 + (ln & 15);
      w1P[s * 32768 + e] = f2bf(w1[(base * 128 + k) * 256 + n] * ln_s[base * 128 + k]);
    } else {
      int e2 = e - 32768;
      int j = e2 & 7, ln = (e2 >> 3) & 63, ks = (e2 >> 9) & 7, nt = e2 >> 12;
      int k = ks * 32 + (ln >> 4) * 8 + j;
      int n = nt * 16 + (ln & 15);
      float te = tf[n] * (1.0f / (1.0f + __expf(-gate[base * 128 + n])));
      w2P[s * 32768 + e2] = f2bf(w2[(base * 256 + k) * 128 + n] * (0.5f * (1.0f + te)));
    }
    return;
  }
  if (bx < 2056) {
    int s = bx - 2048, n = threadIdx.x;
    int base = (s >> 1) * 8 + wsI[s];
    float a = b1[base * 256 + n];
#pragma unroll 16
    for (int k = 0; k < 128; ++k)
      a += ln_b[base * 128 + k] * w1[(base * 128 + k) * 256 + n];
    wsP[s * 384 + n] = a;
    if (n < 128) {
      float te = tf[n] * (1.0f / (1.0f + __expf(-gate[base * 128 + n])));
      wsP[s * 384 + 256 + n] = 0.5f * (1.0f + te) * b2[base * 128 + n];
    }
    return;
  }
  int gid = (bx - 2056) * 256 + threadIdx.x;
  if (gid < 4096) {
    int j = gid & 7, ln = (gid >> 3) & 63, nt = gid >> 9;
    int k = (ln >> 4) * 8 + j, n = nt * 16 + (ln & 15);
    pwP[gid] = f2bf(proj_w[k * 128 + n]);
  } else if (gid < 4224) {
    int d = gid - 4096;
    pb[d] = proj_b[d] + pos[d];
  }
}

// ---------------------------------------------------------------------------
// Kernel B: the batch. 4096 blocks x 256 thr (4 waves), 32 rows/block,
// 4 blocks/CU. B-frags prefetched before the preceding barrier phase.
// ---------------------------------------------------------------------------
__global__ __launch_bounds__(256, 4) void uv6_main(
    const float* __restrict__ x, const float* __restrict__ cls_w,
    const float* __restrict__ cls_b, const float* __restrict__ wsP,
    const float* __restrict__ pb, const ushort_t* __restrict__ pwP,
    const ushort_t* __restrict__ w1P, const ushort_t* __restrict__ w2P,
    float* __restrict__ out) {
  __shared__ float hbuf[TBROWS * HSTR];    // 16896 B
  __shared__ ushort_t frag[16 * 520];      // 16640 B (xP/hnP/z1P phase-unioned)

  const int tid = threadIdx.x;
  const int w = tid >> 6, lane = tid & 63, q = lane >> 4, m0 = lane & 15;
  const int r = tid >> 3, p = tid & 7;     // row / col-part (16 cols each)
  const int rt_r = r >> 4, m_r = r & 15;
  const long rowbase = (long)blockIdx.x * TBROWS;

  // ---- phase 0: x tile [32 x 32] -> A-fragments (bf16, u32 writes) ----
  {
    float4 xv = *(const float4*)(x + (rowbase + r) * 32 + p * 4);
    unsigned u01 = f2bf2(xv.x, xv.y), u23 = f2bf2(xv.z, xv.w);
    ushort_t* dst = &frag[rt_r * 520 + ((p >> 1) * 16 + m_r) * 8 + (p & 1) * 4];
    *(unsigned*)(dst) = u01;
    *(unsigned*)(dst + 2) = u23;
  }
  __syncthreads();

  // ---- projection: h = x @ proj_w + (proj_b+pos) ; wave w: nt {w, w+4} ----
  {
    f32x4 acc[2][2];
    s16x8 bfr[2];
#pragma unroll
    for (int u = 0; u < 2; ++u) {
      int nt = w + 4 * u;
      bfr[u] = *(const s16x8*)(pwP + (nt * 64 + lane) * 8);
      float bv = pb[nt * 16 + m0];
#pragma unroll
      for (int rt = 0; rt < 2; ++rt) acc[rt][u] = (f32x4){bv, bv, bv, bv};
    }
#pragma unroll
    for (int rt = 0; rt < 2; ++rt) {
      s16x8 af = *(const s16x8*)&frag[rt * 520 + lane * 8];
      acc[rt][0] = __builtin_amdgcn_mfma_f32_16x16x32_bf16(af, bfr[0], acc[rt][0], 0, 0, 0);
      acc[rt][1] = __builtin_amdgcn_mfma_f32_16x16x32_bf16(af, bfr[1], acc[rt][1], 0, 0, 0);
    }
#pragma unroll
    for (int rt = 0; rt < 2; ++rt)
#pragma unroll
      for (int u = 0; u < 2; ++u) {
        int col = (w + 4 * u) * 16 + m0;
#pragma unroll
        for (int reg = 0; reg < 4; ++reg)
          hbuf[(rt * 16 + 4 * q + reg) * HSTR + col] = acc[rt][u][reg];
      }
  }
  __syncthreads();

  float* outH = out + (size_t)BATCH * 2;

  // ---- 8 FFN block stages ----
  for (int s = 0; s < 8; ++s) {
    const float* c1 = wsP + s * 384;
    const float* c2 = c1 + 256;
    const ushort_t* w1s = w1P + s * 32768;
    const ushort_t* w2s = w2P + s * 32768;

    // ---- prefetch mm1 B-frags (hidden behind LN) ----
    s16x8 bfr1[4][4];
#pragma unroll
    for (int ni = 0; ni < 4; ++ni)
#pragma unroll
      for (int ks = 0; ks < 4; ++ks)
        bfr1[ni][ks] = *(const s16x8*)(w1s + (((w + ni * 4) * 4 + ks) * 64 + lane) * 8);

    // -- LayerNorm (folded: hn = (h-mu)*rstd) + pack into A-frag layout --
    {
      const float* hr = hbuf + r * HSTR + p * 16;
      float hv[16];
      *(float4*)(hv) = *(const float4*)(hr);
      *(float4*)(hv + 4) = *(const float4*)(hr + 4);
      *(float4*)(hv + 8) = *(const float4*)(hr + 8);
      *(float4*)(hv + 12) = *(const float4*)(hr + 12);
      float sum = 0.0f, ssq = 0.0f;
#pragma unroll
      for (int i = 0; i < 16; ++i) { sum += hv[i]; ssq += hv[i] * hv[i]; }
      sum += __shfl_xor(sum, 1); ssq += __shfl_xor(ssq, 1);
      sum += __shfl_xor(sum, 2); ssq += __shfl_xor(ssq, 2);
      sum += __shfl_xor(sum, 4); ssq += __shfl_xor(ssq, 4);
      float mu = sum * (1.0f / 128.0f);
      float rstd = rsqrtf(ssq * (1.0f / 128.0f) - mu * mu + 1e-5f);
      float nmu = -mu * rstd;
#pragma unroll
      for (int g = 0; g < 2; ++g) {
        union { unsigned u[4]; s16x8 v; } tv;
#pragma unroll
        for (int jj = 0; jj < 4; ++jj) {
          float a = fmaf(hv[g * 8 + jj * 2], rstd, nmu);
          float b = fmaf(hv[g * 8 + jj * 2 + 1], rstd, nmu);
          tv.u[jj] = f2bf2(a, b);
        }
        int kb = p >> 1, qq = (2 * p + g) & 3;
        *(s16x8*)&frag[(rt_r * 4 + kb) * 520 + (qq * 16 + m_r) * 8] = tv.v;
      }
    }
    __syncthreads();

    // -- matmul1: z1 = hn @ w1' + c1' (wave w owns nt {w,w+4,w+8,w+12}) --
    f32x4 a1[2][4];
    {
#pragma unroll
      for (int ni = 0; ni < 4; ++ni) {
        float bv = c1[(w + ni * 4) * 16 + m0];
        a1[0][ni] = (f32x4){bv, bv, bv, bv};
        a1[1][ni] = (f32x4){bv, bv, bv, bv};
      }
#pragma unroll
      for (int ks = 0; ks < 4; ++ks) {
        s16x8 af0 = *(const s16x8*)&frag[ks * 520 + lane * 8];
        s16x8 af1 = *(const s16x8*)&frag[(4 + ks) * 520 + lane * 8];
#pragma unroll
        for (int ni = 0; ni < 4; ++ni) {
          a1[0][ni] = __builtin_amdgcn_mfma_f32_16x16x32_bf16(af0, bfr1[ni][ks], a1[0][ni], 0, 0, 0);
          a1[1][ni] = __builtin_amdgcn_mfma_f32_16x16x32_bf16(af1, bfr1[ni][ks], a1[1][ni], 0, 0, 0);
        }
      }
    }
    __syncthreads();  // all waves done reading hn frags

    // ---- prefetch mm2 B-frags + c2 (hidden behind gelu/scatter) ----
    s16x8 bfr2[2][8];
#pragma unroll
    for (int ni = 0; ni < 2; ++ni)
#pragma unroll
      for (int ks = 0; ks < 8; ++ks)
        bfr2[ni][ks] = *(const s16x8*)(w2s + (((w + ni * 4) * 8 + ks) * 64 + lane) * 8);
    f32x4 a2[2][2];
#pragma unroll
    for (int ni = 0; ni < 2; ++ni) {
      float bv = c2[(w + ni * 4) * 16 + m0];
      a2[0][ni] = (f32x4){bv, bv, bv, bv};
      a2[1][ni] = (f32x4){bv, bv, bv, bv};
    }

    // -- gelu + scatter z1 into matmul2 A-frag layout --
    {
#pragma unroll
      for (int ni = 0; ni < 4; ++ni) {
        int n = (w + ni * 4) * 16 + m0;  // z1 column = matmul2 k
        int kb = n >> 5, qq = (n >> 3) & 3, j = n & 7;
#pragma unroll
        for (int rt = 0; rt < 2; ++rt)
#pragma unroll
          for (int reg = 0; reg < 4; ++reg)
            frag[(rt * 8 + kb) * 520 + (qq * 16 + 4 * q + reg) * 8 + j] =
                f2bf1(geluf(a1[rt][ni][reg]));
      }
    }
    __syncthreads();

    // -- matmul2: z2' = z1 @ w2' + c2' (wave w owns nt2 {w, w+4}) --
    {
#pragma unroll
      for (int ks = 0; ks < 8; ++ks) {
        s16x8 af0 = *(const s16x8*)&frag[ks * 520 + lane * 8];
        s16x8 af1 = *(const s16x8*)&frag[(8 + ks) * 520 + lane * 8];
#pragma unroll
        for (int ni = 0; ni < 2; ++ni) {
          a2[0][ni] = __builtin_amdgcn_mfma_f32_16x16x32_bf16(af0, bfr2[ni][ks], a2[0][ni], 0, 0, 0);
          a2[1][ni] = __builtin_amdgcn_mfma_f32_16x16x32_bf16(af1, bfr2[ni][ks], a2[1][ni], 0, 0, 0);
        }
      }
    }

    // -- epilogue: h += z2' (scaling folded into w2'/c2'; 2-way free banks) --
    {
#pragma unroll
      for (int ni = 0; ni < 2; ++ni) {
        int col = (w + ni * 4) * 16 + m0;
#pragma unroll
        for (int rt = 0; rt < 2; ++rt)
#pragma unroll
          for (int reg = 0; reg < 4; ++reg)
            hbuf[(rt * 16 + 4 * q + reg) * HSTR + col] += a2[rt][ni][reg];
      }
    }
    __syncthreads();
  }

  // ---- h write-out: flat, lane-contiguous float4 (coalesced) ----
#pragma unroll
  for (int it = 0; it < 4; ++it) {
    int p4 = it * 256 + tid;
    int row = p4 >> 5, c = (p4 & 31) * 4;
    float4 o = *(const float4*)(hbuf + row * HSTR + c);
    *(float4*)(outH + rowbase * 128 + p4 * 4) = o;
  }

  // ---- logits = h @ cls_w + cls_b (8 lanes/row, xor-reduce) ----
  {
    const float* hr = hbuf + r * HSTR + p * 16;
    float l0 = 0.0f, l1 = 0.0f;
#pragma unroll
    for (int i = 0; i < 16; i += 4) {
      float4 v = *(const float4*)(hr + i);
      int c = (p * 16 + i) * 2;
      l0 += v.x * cls_w[c] + v.y * cls_w[c + 2] + v.z * cls_w[c + 4] + v.w * cls_w[c + 6];
      l1 += v.x * cls_w[c + 1] + v.y * cls_w[c + 3] + v.z * cls_w[c + 5] + v.w * cls_w[c + 7];
    }
    l0 += __shfl_xor(l0, 1); l1 += __shfl_xor(l1, 1);
    l0 += __shfl_xor(l0, 2); l1 += __shfl_xor(l1, 2);
    l0 += __shfl_xor(l0, 4); l1 += __shfl_xor(l1, 4);
    if (p == 0) {
      float2 lg = {l0 + cls_b[0], l1 + cls_b[1]};
      *(float2*)(out + (rowbase + r) * 2) = lg;
    }
  }
}

// ---------------------------------------------------------------------------
extern "C" void kernel_launch(void* const* d_in, const int* in_sizes, int n_in,
                              void* d_out, int out_size, void* d_ws, size_t ws_size,
                              hipStream_t stream) {
  (void)in_sizes; (void)n_in; (void)out_size; (void)ws_size;
  const float* x      = (const float*)d_in[0];
  const float* proj_w = (const float*)d_in[1];
  const float* proj_b = (const float*)d_in[2];
  const float* pos    = (const float*)d_in[3];
  const float* sel_w  = (const float*)d_in[4];
  const float* sel_b  = (const float*)d_in[5];
  const float* ln_s   = (const float*)d_in[6];
  const float* ln_b   = (const float*)d_in[7];
  const float* w1     = (const float*)d_in[8];
  const float* b1     = (const float*)d_in[9];
  const float* w2     = (const float*)d_in[10];
  const float* b2     = (const float*)d_in[11];
  const float* gate   = (const float*)d_in[12];
  const float* cls_w  = (const float*)d_in[13];
  const float* cls_b  = (const float*)d_in[14];
  const float* tf     = (const float*)d_in[15];

  char* ws = (char*)d_ws;
  int* wsI        = (int*)(ws + WS_IDX);
  float* wsP      = (float*)(ws + WS_PRM);
  float* pb       = (float*)(ws + WS_PB);
  ushort_t* pwP   = (ushort_t*)(ws + WS_PW);
  ushort_t* w1P   = (ushort_t*)(ws + WS_W1);
  ushort_t* w2P   = (ushort_t*)(ws + WS_W2);
  float* outF     = (float*)d_out;

  uv6_select<<<1, 1024, 0, stream>>>(x, proj_w, proj_b, pos, sel_w, sel_b, ln_s,
                                     ln_b, w1, b1, w2, b2, gate, tf, wsI);
  uv6_pack<<<2073, 256, 0, stream>>>(w1, w2, ln_s, ln_b, b1, b2, gate, tf,
                                     proj_w, proj_b, pos, wsI, w1P, w2P, wsP,
                                     pwP, pb);
  uv6_main<<<BATCH / TBROWS, 256, 0, stream>>>(x, cls_w, cls_b, wsP, pb, pwP,
                                               w1P, w2P, outF);
}

// Round 4
// 364.340 us; speedup vs baseline: 1.8970x; 1.2481x over previous
//
#include <hip/hip_runtime.h>

// ---------------------------------------------------------------------------
// UltimateV6 r4: top-k depends only on batch row 0 -> tiny select kernel,
// then batch is a static chain of 8 FFN blocks on bf16 MFMA.
// r4: TBROWS 64 / 512 thr / 2 blocks/CU -> full B-frag prefetch fits in regs
// (r3 spilled ~250MB to scratch); frag LDS re-addressed for write-bank
// spread; warm kernel pre-loads w1/w2 into L2 before the serial select.
// ---------------------------------------------------------------------------

typedef __attribute__((ext_vector_type(8))) short s16x8;
typedef __attribute__((ext_vector_type(4))) float f32x4;
typedef unsigned short ushort_t;

#define BATCH 131072
#define TBROWS 64
#define HSTR 132        // h row stride (floats): %4==0 aligned b128
#define FGSTR 544       // frag group stride (u16)
#define FQSTR 136       // frag k-quad stride (u16): 68 u32 -> qq spreads banks

// ws layout (bytes)
#define WS_IDX 0        // int[8]
#define WS_PRM 64       // float[8][384]: c1'[256] c2'[128]
#define WS_PB  12352    // float[128]: proj_b + pos
#define WS_PW  12864    // ushort[4096]: proj_w frag-packed bf16
#define WS_W1  21056    // ushort[8][32768]  w1' = ln_s-folded
#define WS_W2  545344   // ushort[8][32768]  w2' = 0.5(1+te)-folded
#define WS_DMP 1069632  // float[16] warm-kernel dump

__device__ inline ushort_t f2bf(float f) {         // RNE (cold paths)
  unsigned u = __float_as_uint(f);
  u += 0x7fffu + ((u >> 16) & 1u);
  return (ushort_t)(u >> 16);
}
__device__ inline ushort_t f2bf1(float f) {        // round-half-up, 2 ops
  return (ushort_t)((__float_as_uint(f) + 0x8000u) >> 16);
}
__device__ inline unsigned f2bf2(float lo, float hi) {  // 2 vals -> 1 u32
  unsigned a = __float_as_uint(lo) + 0x8000u;
  unsigned b = __float_as_uint(hi) + 0x8000u;
  return __builtin_amdgcn_perm(b, a, 0x07060302u);  // [b.hi16 : a.hi16]
}

// gelu ~= x * sigmoid(1.702 x)
__device__ inline float geluf(float v) {
  float e = __builtin_amdgcn_exp2f(-2.4554670f * v);
  return v * __builtin_amdgcn_rcpf(1.0f + e);
}

// ---------------------------------------------------------------------------
// Kernel 0: warm w1/w2 (8.4 MB) into L2/L3 so the serial select kernel's
// per-selection 256KB register prefetch hits cache, not cold HBM.
// ---------------------------------------------------------------------------
__global__ __launch_bounds__(256) void uv6_warm(
    const float* __restrict__ w1, const float* __restrict__ w2,
    float* __restrict__ dump) {
  int gid = blockIdx.x * 256 + threadIdx.x;      // 131072 threads
  const float4* a = (const float4*)w1;           // 262144 float4
  const float4* b = (const float4*)w2;
  float s = 0.0f;
#pragma unroll
  for (int i = 0; i < 2; ++i) {
    float4 v = a[gid + i * 131072];
    float4 u = b[gid + i * 131072];
    s += v.x + v.y + v.z + v.w + u.x + u.y + u.z + u.w;
  }
  if (s > 1e30f) dump[0] = s;  // never true for these inputs; keeps loads live
}

// ---------------------------------------------------------------------------
// Kernel A: row-0 trajectory, exact fp32 (erff). 1024 threads; per selection
// both weight matrices prefetched to registers right after the block index
// is known; shfl-based reductions.
// ---------------------------------------------------------------------------
__global__ __launch_bounds__(1024) void uv6_select(
    const float* __restrict__ x, const float* __restrict__ proj_w,
    const float* __restrict__ proj_b, const float* __restrict__ pos,
    const float* __restrict__ sel_w, const float* __restrict__ sel_b,
    const float* __restrict__ ln_s, const float* __restrict__ ln_b,
    const float* __restrict__ w1, const float* __restrict__ b1,
    const float* __restrict__ w2, const float* __restrict__ b2,
    const float* __restrict__ gate, const float* __restrict__ tf,
    int* __restrict__ wsI) {
  __shared__ float h0[128], hn[128], z1[256];
  __shared__ float red[1024];
  __shared__ float wred[128];
  __shared__ float adjs[8];
  __shared__ int top[2];
  __shared__ float stat[2];
  const int t = threadIdx.x;
  const int lane = t & 63, wv = t >> 6;
  const int n1 = t & 255, dp1 = t >> 8;   // mm1 ownership
  const int n2 = t & 127, dp2 = t >> 7;   // mm2 ownership

  if (t < 128) {
    float a = proj_b[t] + pos[t];
#pragma unroll
    for (int f = 0; f < 32; ++f) a += x[f] * proj_w[f * 128 + t];
    h0[t] = a;
  }
  __syncthreads();

  for (int l = 0; l < 4; ++l) {
    {
      float pp = h0[t >> 3] * sel_w[(l * 128 + (t >> 3)) * 8 + (t & 7)];
      pp += __shfl_xor(pp, 8);
      pp += __shfl_xor(pp, 16);
      pp += __shfl_xor(pp, 32);
      if (lane < 8) wred[wv * 8 + lane] = pp;
    }
    __syncthreads();
    if (t < 8) {
      float sc = sel_b[l * 8 + t];
#pragma unroll
      for (int v = 0; v < 16; ++v) sc += wred[v * 8 + t];
      sc = 1.0f / (1.0f + __expf(-sc));
      adjs[t] = sc * 0.6f + 0.2f;  // priority 0.5 * 0.4
    }
    __syncthreads();
    if (t == 0) {
      int i0 = 0; float v0 = adjs[0];
      for (int j = 1; j < 8; ++j) if (adjs[j] > v0) { v0 = adjs[j]; i0 = j; }
      int i1 = -1; float v1 = -1e30f;
      for (int j = 0; j < 8; ++j) if (j != i0 && adjs[j] > v1) { v1 = adjs[j]; i1 = j; }
      top[0] = i0; top[1] = i1;
      wsI[2 * l] = i0; wsI[2 * l + 1] = i1;
    }
    __syncthreads();
    for (int kk = 0; kk < 2; ++kk) {
      const int base = l * 8 + top[kk];
      float w1v[32], w2v[32];
      const float* w1p = w1 + (base * 128 + dp1 * 32) * 256 + n1;
      const float* w2p = w2 + (base * 256 + dp2 * 32) * 128 + n2;
#pragma unroll
      for (int j = 0; j < 32; ++j) w1v[j] = w1p[j * 256];
#pragma unroll
      for (int j = 0; j < 32; ++j) w2v[j] = w2p[j * 128];
      if (t < 64) {
        float a = h0[t], b = h0[t + 64];
        float s2 = a + b, q2 = a * a + b * b;
        s2 += __shfl_xor(s2, 1);  q2 += __shfl_xor(q2, 1);
        s2 += __shfl_xor(s2, 2);  q2 += __shfl_xor(q2, 2);
        s2 += __shfl_xor(s2, 4);  q2 += __shfl_xor(q2, 4);
        s2 += __shfl_xor(s2, 8);  q2 += __shfl_xor(q2, 8);
        s2 += __shfl_xor(s2, 16); q2 += __shfl_xor(q2, 16);
        s2 += __shfl_xor(s2, 32); q2 += __shfl_xor(q2, 32);
        if (t == 0) {
          float mu = s2 * (1.0f / 128.0f);
          stat[0] = mu;
          stat[1] = rsqrtf(q2 * (1.0f / 128.0f) - mu * mu + 1e-5f);
        }
      }
      __syncthreads();
      if (t < 128)
        hn[t] = (h0[t] - stat[0]) * stat[1] * ln_s[base * 128 + t] + ln_b[base * 128 + t];
      __syncthreads();
      {
        float a = 0.0f;
#pragma unroll
        for (int j = 0; j < 32; ++j) a += hn[dp1 * 32 + j] * w1v[j];
        red[dp1 * 256 + n1] = a;
      }
      __syncthreads();
      if (t < 256) {
        float z = red[t] + red[256 + t] + red[512 + t] + red[768 + t] + b1[base * 256 + t];
        z1[t] = z * 0.5f * (1.0f + erff(z * 0.70710678118f));  // exact gelu
      }
      __syncthreads();
      {
        float a = 0.0f;
#pragma unroll
        for (int j = 0; j < 32; ++j) a += z1[dp2 * 32 + j] * w2v[j];
        red[dp2 * 128 + n2] = a;
      }
      __syncthreads();
      if (t < 128) {
        float z2 = b2[base * 128 + t];
#pragma unroll
        for (int v = 0; v < 8; ++v) z2 += red[v * 128 + t];
        float te = tf[t] * (1.0f / (1.0f + __expf(-gate[base * 128 + t])));
        h0[t] += 0.5f * z2 * (1.0f + te);
      }
      __syncthreads();
    }
  }
}

// ---------------------------------------------------------------------------
// Kernel P: blocks 0..2047 pack w1'(=ln_s-folded) / w2'(=0.5(1+te)-folded)
// B-fragments; blocks 2048..2055 compute c1'= b1 + ln_b@w1 and
// c2'= 0.5(1+te).b2; blocks 2056.. pack proj fragments + pb.
// ---------------------------------------------------------------------------
__global__ __launch_bounds__(256) void uv6_pack(
    const float* __restrict__ w1, const float* __restrict__ w2,
    const float* __restrict__ ln_s, const float* __restrict__ ln_b,
    const float* __restrict__ b1, const float* __restrict__ b2,
    const float* __restrict__ gate, const float* __restrict__ tf,
    const float* __restrict__ proj_w, const float* __restrict__ proj_b,
    const float* __restrict__ pos, const int* __restrict__ wsI,
    ushort_t* __restrict__ w1P, ushort_t* __restrict__ w2P,
    float* __restrict__ wsP, ushort_t* __restrict__ pwP,
    float* __restrict__ pb) {
  const int bx = blockIdx.x;
  if (bx < 2048) {
    int gid = bx * 256 + threadIdx.x;
    int s = gid >> 16, e = gid & 65535;
    int base = (s >> 1) * 8 + wsI[s];
    if (e < 32768) {
      int j = e & 7, ln = (e >> 3) & 63, ks = (e >> 9) & 3, nt = e >> 11;
      int k = ks * 32 + (ln >> 4) * 8 + j;
      int n = nt * 16 + (ln & 15);
      w1P[s * 32768 + e] = f2bf(w1[(base * 128 + k) * 256 + n] * ln_s[base * 128 + k]);
    } else {
      int e2 = e - 32768;
      int j = e2 & 7, ln = (e2 >> 3) & 63, ks = (e2 >> 9) & 7, nt = e2 >> 12;
      int k = ks * 32 + (ln >> 4) * 8 + j;
      int n = nt * 16 + (ln & 15);
      float te = tf[n] * (1.0f / (1.0f + __expf(-gate[base * 128 + n])));
      w2P[s * 32768 + e2] = f2bf(w2[(base * 256 + k) * 128 + n] * (0.5f * (1.0f + te)));
    }
    return;
  }
  if (bx < 2056) {
    int s = bx - 2048, n = threadIdx.x;
    int base = (s >> 1) * 8 + wsI[s];
    float a = b1[base * 256 + n];
#pragma unroll 16
    for (int k = 0; k < 128; ++k)
      a += ln_b[base * 128 + k] * w1[(base * 128 + k) * 256 + n];
    wsP[s * 384 + n] = a;
    if (n < 128) {
      float te = tf[n] * (1.0f / (1.0f + __expf(-gate[base * 128 + n])));
      wsP[s * 384 + 256 + n] = 0.5f * (1.0f + te) * b2[base * 128 + n];
    }
    return;
  }
  int gid = (bx - 2056) * 256 + threadIdx.x;
  if (gid < 4096) {
    int j = gid & 7, ln = (gid >> 3) & 63, nt = gid >> 9;
    int k = (ln >> 4) * 8 + j, n = nt * 16 + (ln & 15);
    pwP[gid] = f2bf(proj_w[k * 128 + n]);
  } else if (gid < 4224) {
    int d = gid - 4096;
    pb[d] = proj_b[d] + pos[d];
  }
}

// ---------------------------------------------------------------------------
// Kernel B: the batch. 2048 blocks x 512 thr (8 waves), 64 rows/block,
// 2 blocks/CU (LDS 68.6KB). Wave w owns mm1 nt {2w,2w+1}, mm2 nt {w} ->
// all B-frags prefetchable in regs without spill. Frag LDS groups:
// g = rt*8 + kb, element (kq,m,j) at g*544 + kq*136 + m*8 + j.
// ---------------------------------------------------------------------------
__global__ __launch_bounds__(512, 2) void uv6_main(
    const float* __restrict__ x, const float* __restrict__ cls_w,
    const float* __restrict__ cls_b, const float* __restrict__ wsP,
    const float* __restrict__ pb, const ushort_t* __restrict__ pwP,
    const ushort_t* __restrict__ w1P, const ushort_t* __restrict__ w2P,
    float* __restrict__ out) {
  __shared__ float hbuf[TBROWS * HSTR];      // 33792 B
  __shared__ ushort_t frag[32 * FGSTR];      // 34816 B (x/hn/z1 phase-unioned)

  const int tid = threadIdx.x;
  const int w = tid >> 6, lane = tid & 63, q = lane >> 4, m0 = lane & 15;
  const int r = tid >> 3, p = tid & 7;       // row / col-part (16 cols each)
  const int rt_r = r >> 4, m_r = r & 15;
  const long rowbase = (long)blockIdx.x * TBROWS;

  // ---- phase 0: x tile [64 x 32] -> A-fragments (bf16) ----
  {
    float4 xv = *(const float4*)(x + (rowbase + r) * 32 + p * 4);
    unsigned u01 = f2bf2(xv.x, xv.y), u23 = f2bf2(xv.z, xv.w);
    ushort_t* dst = &frag[(rt_r * 8) * FGSTR + (p >> 1) * FQSTR + m_r * 8 + (p & 1) * 4];
    *(unsigned*)dst = u01;
    *(unsigned*)(dst + 2) = u23;
  }
  __syncthreads();

  // ---- projection: h = x @ proj_w + (proj_b+pos) ; wave w owns nt = w ----
  {
    s16x8 bfr = *(const s16x8*)(pwP + (w * 64 + lane) * 8);
    float bv = pb[w * 16 + m0];
    f32x4 acc[4];
#pragma unroll
    for (int rt = 0; rt < 4; ++rt) acc[rt] = (f32x4){bv, bv, bv, bv};
#pragma unroll
    for (int rt = 0; rt < 4; ++rt) {
      s16x8 af = *(const s16x8*)&frag[(rt * 8) * FGSTR + q * FQSTR + m0 * 8];
      acc[rt] = __builtin_amdgcn_mfma_f32_16x16x32_bf16(af, bfr, acc[rt], 0, 0, 0);
    }
    int col = w * 16 + m0;
#pragma unroll
    for (int rt = 0; rt < 4; ++rt)
#pragma unroll
      for (int reg = 0; reg < 4; ++reg)
        hbuf[(rt * 16 + 4 * q + reg) * HSTR + col] = acc[rt][reg];
  }
  __syncthreads();

  float* outH = out + (size_t)BATCH * 2;

  // ---- 8 FFN block stages ----
  for (int s = 0; s < 8; ++s) {
    const float* c1 = wsP + s * 384;
    const float* c2 = c1 + 256;
    const ushort_t* w1s = w1P + s * 32768;
    const ushort_t* w2s = w2P + s * 32768;

    // ---- prefetch mm1 B-frags (hidden behind LN) ----
    s16x8 bfr1[2][4];
#pragma unroll
    for (int ni = 0; ni < 2; ++ni)
#pragma unroll
      for (int ks = 0; ks < 4; ++ks)
        bfr1[ni][ks] = *(const s16x8*)(w1s + (((2 * w + ni) * 4 + ks) * 64 + lane) * 8);

    // -- LayerNorm (folded: hn = (h-mu)*rstd) + pack into A-frag layout --
    {
      const float* hr = hbuf + r * HSTR + p * 16;
      float hv[16];
      *(float4*)(hv) = *(const float4*)(hr);
      *(float4*)(hv + 4) = *(const float4*)(hr + 4);
      *(float4*)(hv + 8) = *(const float4*)(hr + 8);
      *(float4*)(hv + 12) = *(const float4*)(hr + 12);
      float sum = 0.0f, ssq = 0.0f;
#pragma unroll
      for (int i = 0; i < 16; ++i) { sum += hv[i]; ssq += hv[i] * hv[i]; }
      sum += __shfl_xor(sum, 1); ssq += __shfl_xor(ssq, 1);
      sum += __shfl_xor(sum, 2); ssq += __shfl_xor(ssq, 2);
      sum += __shfl_xor(sum, 4); ssq += __shfl_xor(ssq, 4);
      float mu = sum * (1.0f / 128.0f);
      float rstd = rsqrtf(ssq * (1.0f / 128.0f) - mu * mu + 1e-5f);
      float nmu = -mu * rstd;
#pragma unroll
      for (int g = 0; g < 2; ++g) {
        union { unsigned u[4]; s16x8 v; } tv;
#pragma unroll
        for (int jj = 0; jj < 4; ++jj) {
          float a = fmaf(hv[g * 8 + jj * 2], rstd, nmu);
          float b = fmaf(hv[g * 8 + jj * 2 + 1], rstd, nmu);
          tv.u[jj] = f2bf2(a, b);
        }
        int kb = p >> 1, qq = (2 * p + g) & 3;
        *(s16x8*)&frag[(rt_r * 8 + kb) * FGSTR + qq * FQSTR + m_r * 8] = tv.v;
      }
    }
    __syncthreads();

    // -- matmul1: z1 = hn @ w1' + c1' (wave w owns nt {2w, 2w+1}) --
    f32x4 a1[4][2];
    {
#pragma unroll
      for (int ni = 0; ni < 2; ++ni) {
        float bv = c1[(2 * w + ni) * 16 + m0];
#pragma unroll
        for (int rt = 0; rt < 4; ++rt) a1[rt][ni] = (f32x4){bv, bv, bv, bv};
      }
#pragma unroll
      for (int ks = 0; ks < 4; ++ks) {
        s16x8 af[4];
#pragma unroll
        for (int rt = 0; rt < 4; ++rt)
          af[rt] = *(const s16x8*)&frag[(rt * 8 + ks) * FGSTR + q * FQSTR + m0 * 8];
#pragma unroll
        for (int rt = 0; rt < 4; ++rt)
#pragma unroll
          for (int ni = 0; ni < 2; ++ni)
            a1[rt][ni] = __builtin_amdgcn_mfma_f32_16x16x32_bf16(af[rt], bfr1[ni][ks], a1[rt][ni], 0, 0, 0);
      }
    }
    __syncthreads();  // all waves done reading hn frags

    // ---- prefetch mm2 B-frags + c2 (hidden behind gelu/scatter) ----
    s16x8 bfr2[8];
#pragma unroll
    for (int ks = 0; ks < 8; ++ks)
      bfr2[ks] = *(const s16x8*)(w2s + ((w * 8 + ks) * 64 + lane) * 8);
    f32x4 a2[4];
    {
      float bv = c2[w * 16 + m0];
#pragma unroll
      for (int rt = 0; rt < 4; ++rt) a2[rt] = (f32x4){bv, bv, bv, bv};
    }

    // -- gelu + scatter z1 into mm2 A-frag layout (kb = w for both ni) --
    {
      int j = m0 & 7;
#pragma unroll
      for (int ni = 0; ni < 2; ++ni) {
        int qq = (2 * ni + (m0 >> 3)) & 3;
#pragma unroll
        for (int rt = 0; rt < 4; ++rt)
#pragma unroll
          for (int reg = 0; reg < 4; ++reg)
            frag[(rt * 8 + w) * FGSTR + qq * FQSTR + (4 * q + reg) * 8 + j] =
                f2bf1(geluf(a1[rt][ni][reg]));
      }
    }
    __syncthreads();

    // -- matmul2: z2' = z1 @ w2' + c2' (wave w owns nt2 = w) --
    {
#pragma unroll
      for (int kb = 0; kb < 8; ++kb) {
        s16x8 af[4];
#pragma unroll
        for (int rt = 0; rt < 4; ++rt)
          af[rt] = *(const s16x8*)&frag[(rt * 8 + kb) * FGSTR + q * FQSTR + m0 * 8];
#pragma unroll
        for (int rt = 0; rt < 4; ++rt)
          a2[rt] = __builtin_amdgcn_mfma_f32_16x16x32_bf16(af[rt], bfr2[kb], a2[rt], 0, 0, 0);
      }
    }

    // -- epilogue: h += z2' (scaling folded into w2'/c2'; conflict-free) --
    {
      int col = w * 16 + m0;
#pragma unroll
      for (int rt = 0; rt < 4; ++rt)
#pragma unroll
        for (int reg = 0; reg < 4; ++reg)
          hbuf[(rt * 16 + 4 * q + reg) * HSTR + col] += a2[rt][reg];
    }
    __syncthreads();
  }

  // ---- h write-out: flat, lane-contiguous float4 (coalesced) ----
#pragma unroll
  for (int it = 0; it < 4; ++it) {
    int p4 = it * 512 + tid;
    int row = p4 >> 5, c = (p4 & 31) * 4;
    float4 o = *(const float4*)(hbuf + row * HSTR + c);
    *(float4*)(outH + rowbase * 128 + p4 * 4) = o;
  }

  // ---- logits = h @ cls_w + cls_b (8 lanes/row, xor-reduce) ----
  {
    const float* hr = hbuf + r * HSTR + p * 16;
    float l0 = 0.0f, l1 = 0.0f;
#pragma unroll
    for (int i = 0; i < 16; i += 4) {
      float4 v = *(const float4*)(hr + i);
      int c = (p * 16 + i) * 2;
      l0 += v.x * cls_w[c] + v.y * cls_w[c + 2] + v.z * cls_w[c + 4] + v.w * cls_w[c + 6];
      l1 += v.x * cls_w[c + 1] + v.y * cls_w[c + 3] + v.z * cls_w[c + 5] + v.w * cls_w[c + 7];
    }
    l0 += __shfl_xor(l0, 1); l1 += __shfl_xor(l1, 1);
    l0 += __shfl_xor(l0, 2); l1 += __shfl_xor(l1, 2);
    l0 += __shfl_xor(l0, 4); l1 += __shfl_xor(l1, 4);
    if (p == 0) {
      float2 lg = {l0 + cls_b[0], l1 + cls_b[1]};
      *(float2*)(out + (rowbase + r) * 2) = lg;
    }
  }
}

// ---------------------------------------------------------------------------
extern "C" void kernel_launch(void* const* d_in, const int* in_sizes, int n_in,
                              void* d_out, int out_size, void* d_ws, size_t ws_size,
                              hipStream_t stream) {
  (void)in_sizes; (void)n_in; (void)out_size; (void)ws_size;
  const float* x      = (const float*)d_in[0];
  const float* proj_w = (const float*)d_in[1];
  const float* proj_b = (const float*)d_in[2];
  const float* pos    = (const float*)d_in[3];
  const float* sel_w  = (const float*)d_in[4];
  const float* sel_b  = (const float*)d_in[5];
  const float* ln_s   = (const float*)d_in[6];
  const float* ln_b   = (const float*)d_in[7];
  const float* w1     = (const float*)d_in[8];
  const float* b1     = (const float*)d_in[9];
  const float* w2     = (const float*)d_in[10];
  const float* b2     = (const float*)d_in[11];
  const float* gate   = (const float*)d_in[12];
  const float* cls_w  = (const float*)d_in[13];
  const float* cls_b  = (const float*)d_in[14];
  const float* tf     = (const float*)d_in[15];

  char* ws = (char*)d_ws;
  int* wsI        = (int*)(ws + WS_IDX);
  float* wsP      = (float*)(ws + WS_PRM);
  float* pb       = (float*)(ws + WS_PB);
  ushort_t* pwP   = (ushort_t*)(ws + WS_PW);
  ushort_t* w1P   = (ushort_t*)(ws + WS_W1);
  ushort_t* w2P   = (ushort_t*)(ws + WS_W2);
  float* dump     = (float*)(ws + WS_DMP);
  float* outF     = (float*)d_out;

  uv6_warm<<<512, 256, 0, stream>>>(w1, w2, dump);
  uv6_select<<<1, 1024, 0, stream>>>(x, proj_w, proj_b, pos, sel_w, sel_b, ln_s,
                                     ln_b, w1, b1, w2, b2, gate, tf, wsI);
  uv6_pack<<<2073, 256, 0, stream>>>(w1, w2, ln_s, ln_b, b1, b2, gate, tf,
                                     proj_w, proj_b, pos, wsI, w1P, w2P, wsP,
                                     pwP, pb);
  uv6_main<<<BATCH / TBROWS, 512, 0, stream>>>(x, cls_w, cls_b, wsP, pb, pwP,
                                               w1P, w2P, outF);
}